// Round 6
// baseline (799.997 us; speedup 1.0000x reference)
//
#include <hip/hip_runtime.h>
#include <hip/hip_fp16.h>

#define B_  4
#define S_  2048
#define DM_ 1024
#define H_  8
#define SCALE_ 0.03125f      // 1/sqrt(1024)
#define NEGS_  (-1e9f)

typedef _Float16 h8 __attribute__((ext_vector_type(8)));
typedef float    f32x4 __attribute__((ext_vector_type(4)));

#define OUT_O ((size_t)B_ * S_ * DM_)            // 8388608 floats (outputs region)
#define SS_   ((size_t)S_ * S_)                  // 4194304 floats per head slot (16 MiB)
#define WPB_  ((size_t)H_ * S_ * S_)             // weights floats per batch

// ---------------- f32 -> f16 convert (vectorized, G13) ----------------
__global__ __launch_bounds__(256) void cvt_f32_f16(const float* __restrict__ in,
                                                   _Float16* __restrict__ out) {
    size_t i = (size_t)blockIdx.x * 256 + threadIdx.x;   // one h8 per thread
    const float4* p = (const float4*)in;
    float4 a = p[2 * i], b = p[2 * i + 1];
    h8 h;
    h[0] = (_Float16)a.x; h[1] = (_Float16)a.y; h[2] = (_Float16)a.z; h[3] = (_Float16)a.w;
    h[4] = (_Float16)b.x; h[5] = (_Float16)b.y; h[6] = (_Float16)b.z; h[7] = (_Float16)b.w;
    ((h8*)out)[i] = h;
}

// ---------------- V [B,S,DM] f32 -> Vt [B,DM,S] f16 (LDS tile transpose) ----------------
__global__ __launch_bounds__(256) void v_transpose(const float* __restrict__ V,
                                                   _Float16* __restrict__ Vt) {
    __shared__ _Float16 tile[64][72];   // +8 pad spreads transposed reads across banks
    int b = blockIdx.z;
    int s0 = blockIdx.y * 64, d0 = blockIdx.x * 64;
    int t = threadIdx.x;
    const float* src = V + ((size_t)b * S_ + s0) * DM_ + d0;
#pragma unroll
    for (int i = 0; i < 4; ++i) {
        int g = t + i * 256;            // 1024 float4 slots
        int r = g >> 4, c = (g & 15) * 4;
        float4 v = *(const float4*)(src + (size_t)r * DM_ + c);
        tile[r][c + 0] = (_Float16)v.x; tile[r][c + 1] = (_Float16)v.y;
        tile[r][c + 2] = (_Float16)v.z; tile[r][c + 3] = (_Float16)v.w;
    }
    __syncthreads();
    int d = t >> 2, sc = (t & 3) * 16;  // each thread: 16 s-values of one d-row
    _Float16 tmp[16];
#pragma unroll
    for (int j = 0; j < 16; ++j) tmp[j] = tile[sc + j][d];
    _Float16* dst = Vt + ((size_t)b * DM_ + d0 + d) * S_ + s0 + sc;
    *(h8*)dst       = *(const h8*)tmp;
    *(h8*)(dst + 8) = *(const h8*)(tmp + 8);
}

// ---------------- NT f16 GEMM, m97 structure: 128x128 tile, BK=64, global_load_lds ----------------
// C[row,col] = sum_k A[row,k] * B[col,k]   (A: lda-strided rows, B: ldb-strided rows)
// QK=true epilogue: C = C*SCALE + mask[row,col]*NEGS
template <bool QK>
__global__ __launch_bounds__(256) void gemm_nt(const _Float16* __restrict__ A,
                                               const _Float16* __restrict__ Bm,
                                               float* __restrict__ C,
                                               const float* __restrict__ mask,
                                               size_t sA, size_t sB, size_t sC,
                                               int lda, int ldb, int ldc, int ksteps) {
    __shared__ _Float16 As[128 * 64];
    __shared__ _Float16 Bs[128 * 64];
    int b = blockIdx.z, brow = blockIdx.y, bcol = blockIdx.x;
    int t = threadIdx.x, lane = t & 63, wid = t >> 6;
    int wr = wid >> 1, wc = wid & 1;            // 2x2 wave grid, 64x64 per wave
    f32x4 acc[4][4];
#pragma unroll
    for (int m = 0; m < 4; ++m)
#pragma unroll
        for (int n = 0; n < 4; ++n) acc[m][n] = (f32x4){0.f, 0.f, 0.f, 0.f};

    const _Float16* Ag = A + (size_t)b * sA + (size_t)(brow * 128) * lda;
    const _Float16* Bg = Bm + (size_t)b * sB + (size_t)(bcol * 128) * ldb;

    for (int ks = 0; ks < ksteps; ++ks) {
        int k0 = ks * 64;
        // stage A,B tiles (128x64 f16 each) via direct global->LDS, 16B/lane
#pragma unroll
        for (int i = 0; i < 4; ++i) {
            int g = t + i * 256;                 // 1024 groups of 8 halves
            int row = g >> 3, kg = (g & 7) * 8;
            __builtin_amdgcn_global_load_lds(
                (const __attribute__((address_space(1))) void*)(Ag + (size_t)row * lda + k0 + kg),
                (__attribute__((address_space(3))) void*)(&As[g * 8]), 16, 0, 0);
        }
#pragma unroll
        for (int i = 0; i < 4; ++i) {
            int g = t + i * 256;
            int row = g >> 3, kg = (g & 7) * 8;
            __builtin_amdgcn_global_load_lds(
                (const __attribute__((address_space(1))) void*)(Bg + (size_t)row * ldb + k0 + kg),
                (__attribute__((address_space(3))) void*)(&Bs[g * 8]), 16, 0, 0);
        }
        __syncthreads();   // compiler drains vmcnt(0) before s_barrier
#pragma unroll
        for (int kk = 0; kk < 2; ++kk) {
            h8 af[4], bf[4];
#pragma unroll
            for (int m = 0; m < 4; ++m)
                af[m] = *(const h8*)&As[(wr * 64 + m * 16 + (lane & 15)) * 64 + kk * 32 + (lane >> 4) * 8];
#pragma unroll
            for (int n = 0; n < 4; ++n)
                bf[n] = *(const h8*)&Bs[(wc * 64 + n * 16 + (lane & 15)) * 64 + kk * 32 + (lane >> 4) * 8];
#pragma unroll
            for (int m = 0; m < 4; ++m)
#pragma unroll
                for (int n = 0; n < 4; ++n)
                    acc[m][n] = __builtin_amdgcn_mfma_f32_16x16x32_f16(af[m], bf[n], acc[m][n], 0, 0, 0);
        }
        __syncthreads();
    }

    // epilogue: C/D layout col=lane&15, row=(lane>>4)*4+reg (m89-verified)
    float* Cb = C + (size_t)b * sC;
#pragma unroll
    for (int m = 0; m < 4; ++m)
#pragma unroll
        for (int n = 0; n < 4; ++n)
#pragma unroll
            for (int r = 0; r < 4; ++r) {
                int row = brow * 128 + wr * 64 + m * 16 + (lane >> 4) * 4 + r;
                int col = bcol * 128 + wc * 64 + n * 16 + (lane & 15);
                float v = acc[m][n][r];
                if (QK) v = v * SCALE_ + mask[(size_t)row * S_ + col] * NEGS_;
                Cb[(size_t)row * ldc + col] = v;
            }
}

// ---------------- row softmax (in-place on head-0 slot) + f16 copy ----------------
__global__ __launch_bounds__(256) void softmax_rows(float* __restrict__ Wout,
                                                    _Float16* __restrict__ Wh) {
    int q = blockIdx.x, b = blockIdx.y;
    int t = threadIdx.x, lane = t & 63, wid = t >> 6;
    float* row0 = Wout + (size_t)b * WPB_ + (size_t)q * S_;   // head-0 slot holds raw scores
    float4 v0 = ((const float4*)row0)[t * 2];
    float4 v1 = ((const float4*)row0)[t * 2 + 1];
    float p[8] = {v0.x, v0.y, v0.z, v0.w, v1.x, v1.y, v1.z, v1.w};

    float mx = p[0];
#pragma unroll
    for (int j = 1; j < 8; ++j) mx = fmaxf(mx, p[j]);
#pragma unroll
    for (int o = 32; o >= 1; o >>= 1) mx = fmaxf(mx, __shfl_down(mx, o));
    __shared__ float red[4];
    if (lane == 0) red[wid] = mx;
    __syncthreads();
    mx = fmaxf(fmaxf(red[0], red[1]), fmaxf(red[2], red[3]));
    __syncthreads();

    float s = 0.f;
#pragma unroll
    for (int j = 0; j < 8; ++j) { p[j] = __expf(p[j] - mx); s += p[j]; }
#pragma unroll
    for (int o = 32; o >= 1; o >>= 1) s += __shfl_down(s, o);
    if (lane == 0) red[wid] = s;
    __syncthreads();
    s = red[0] + red[1] + red[2] + red[3];
    float inv = 1.f / s;
#pragma unroll
    for (int j = 0; j < 8; ++j) p[j] *= inv;

    // f16 copy for the PV GEMM
    h8 h;
#pragma unroll
    for (int j = 0; j < 8; ++j) h[j] = (_Float16)p[j];
    *((h8*)(Wh + ((size_t)b * S_ + q) * S_) + t) = h;

    // normalized f32 back to head-0 slot (in place)
    float4 w0 = {p[0], p[1], p[2], p[3]}, w1 = {p[4], p[5], p[6], p[7]};
    float4* dst = (float4*)row0;
    dst[t * 2] = w0;
    dst[t * 2 + 1] = w1;
}

// ---------------- replicate head-0 slot into heads 1..7 (runs LAST) ----------------
__global__ __launch_bounds__(256) void bcast_heads(float* __restrict__ W) {
    int b = blockIdx.y;
    float* base = W + (size_t)b * WPB_;
    size_t n4 = SS_ / 4;                         // float4s per head slot
    for (size_t off = (size_t)blockIdx.x * 256 + threadIdx.x; off < n4;
         off += (size_t)gridDim.x * 256) {
        float4 v = ((const float4*)base)[off];
#pragma unroll
        for (int hh = 1; hh < H_; ++hh)
            ((float4*)(base + (size_t)hh * SS_))[off] = v;
    }
}

extern "C" void kernel_launch(void* const* d_in, const int* in_sizes, int n_in,
                              void* d_out, int out_size, void* d_ws, size_t ws_size,
                              hipStream_t stream) {
    const float* Q = (const float*)d_in[0];
    const float* K = (const float*)d_in[1];
    const float* V = (const float*)d_in[2];
    const float* mask = (const float*)d_in[3];
    float* outputs = (float*)d_out;              // [B,S,DM]
    float* weights = (float*)d_out + OUT_O;      // [B,H,S,S]

    // Scratch lives in dead weights slots (batch 0, heads 1..5) — no d_ws needed.
    // Each head slot is 16 MiB. Overwritten by bcast_heads at the very end.
    _Float16* Qh = (_Float16*)(weights + 1 * SS_);        // b0 h1
    _Float16* Kh = (_Float16*)(weights + 2 * SS_);        // b0 h2
    _Float16* Vt = (_Float16*)(weights + 3 * SS_);        // b0 h3
    _Float16* Wh = (_Float16*)(weights + 4 * SS_);        // b0 h4+h5 (32 MiB exactly)

    cvt_f32_f16<<<4096, 256, 0, stream>>>(Q, Qh);
    cvt_f32_f16<<<4096, 256, 0, stream>>>(K, Kh);
    v_transpose<<<dim3(16, 32, 4), 256, 0, stream>>>(V, Vt);

    // scores -> head-0 slot of each batch's weights
    gemm_nt<true><<<dim3(16, 16, 4), 256, 0, stream>>>(
        Qh, Kh, weights, mask,
        (size_t)S_ * DM_, (size_t)S_ * DM_, WPB_, DM_, DM_, S_, DM_ / 64);

    softmax_rows<<<dim3(S_, B_), 256, 0, stream>>>(weights, Wh);

    // outputs = w @ V  (A = Wh [S,S] f16, B = Vt [DM,S] f16, both k-contiguous)
    gemm_nt<false><<<dim3(8, 16, 4), 256, 0, stream>>>(
        Wh, Vt, outputs, nullptr,
        SS_, (size_t)DM_ * S_, (size_t)S_ * DM_, S_, S_, DM_, S_ / 64);

    // replicate head-0 -> heads 1..7 (overwrites scratch, runs last)
    bcast_heads<<<dim3(1024, B_), 256, 0, stream>>>(weights);
}